// Round 7
// baseline (615.991 us; speedup 1.0000x reference)
//
#include <hip/hip_runtime.h>
#include <hip/hip_bf16.h>

// MultiExpertLoRALinear on MI355X.
// Round 6 (resubmit; R6 bench never acquired a GPU): GEMM ported to the 256x256
// 8-phase structure (T2 swizzle + T3 phase interleave + T4 covered waitcnt +
// T5 setprio). Per K-tile: 4 phases, staging front-loaded into phases 0-1 so
// the single per-tile vmcnt(0) has ~3 phases (48 MFMA) of cover, vs R2's
// zero-cover drain per step. Small kernels unchanged (isolates gemm delta; if
// new gemm < router duration, router_fused5 enters top-5 and the ~260us
// residual finally decomposes).
// Pipeline:
//   convert_w3    : wh[o][KP] fp16 = [W_base | Bcat | 0]; vh[48][H] fp16.
//   router_fused5 : x -> fp16 (reg) -> xh main cols + z = x*vh^T via MFMA,
//                   16-wave in-block reduce, softmax, c cols + zero pad.
//   gemm          : fp16 MFMA GEMM [M, O, KP=4160], 256x256 tile, BK=64,
//                   8 waves (2Mx4N), 128 KiB LDS (2 slots), XOR-swizzle,
//                   global_load_lds staging, 4-phase/tile schedule.

typedef _Float16 f16x8 __attribute__((ext_vector_type(8)));
typedef float    f32x4 __attribute__((ext_vector_type(4)));

constexpr int H  = 4096;
constexpr int O  = 4096;
constexpr int KP = 4160;   // 4096 + 32 (c cols) + 32 zero pad
constexpr int EA = 4;
constexpr float SCALING_F = 2.0f;  // alpha/rank

typedef const __attribute__((address_space(1))) void gvoid;
typedef __attribute__((address_space(3))) void svoid;

__device__ inline void gload16(const void* g, void* s) {
  __builtin_amdgcn_global_load_lds((gvoid*)g, (svoid*)s, 16, 0, 0);
}

// ---------------------------------------------------------------------------
// Kernel 1: build wh and vh. Block o < O: wh row o. Block O+j: vh row j.
// ---------------------------------------------------------------------------
__global__ __launch_bounds__(256) void convert_w3_kernel(
    const float* __restrict__ W, const float* __restrict__ lora_B,
    const float* __restrict__ lora_A, const float* __restrict__ router_W,
    const int* __restrict__ active, _Float16* __restrict__ wh,
    _Float16* __restrict__ vh) {
  const int bid = blockIdx.x;
  const int tid = threadIdx.x;
  if (bid < O) {
    const int o = bid;
    const float* wrow = W + (size_t)o * H;
    _Float16* dstrow = wh + (size_t)o * KP;
    for (int g = tid; g < 520; g += 256) {
      const int k = g * 8;
      float v[8];
      if (k < H) {
        float4 a = *(const float4*)(wrow + k), b = *(const float4*)(wrow + k + 4);
        v[0] = a.x; v[1] = a.y; v[2] = a.z; v[3] = a.w;
        v[4] = b.x; v[5] = b.y; v[6] = b.z; v[7] = b.w;
      } else if (k < H + 32) {
        const int e = (k - H) >> 3;
        const float* s = lora_B + ((size_t)active[e] * O + o) * 8;  // [E,O,r]
        float4 a = *(const float4*)s, b = *(const float4*)(s + 4);
        v[0] = a.x; v[1] = a.y; v[2] = a.z; v[3] = a.w;
        v[4] = b.x; v[5] = b.y; v[6] = b.z; v[7] = b.w;
      } else {
#pragma unroll
        for (int i = 0; i < 8; ++i) v[i] = 0.f;
      }
      f16x8 h;
#pragma unroll
      for (int i = 0; i < 8; ++i) h[i] = (_Float16)v[i];
      *(f16x8*)(dstrow + k) = h;
    }
  } else {
    const int j = bid - O;          // 0..47
    const float* src = nullptr;
    if (j < 32)      src = lora_A + (size_t)(active[j >> 3] * 8 + (j & 7)) * H;
    else if (j < 36) src = router_W + (size_t)active[j - 32] * H;
    _Float16* dstrow = vh + (size_t)j * H;
    for (int g = tid; g < 512; g += 256) {
      const int k = g * 8;
      f16x8 h;
      if (src) {
        float4 a = *(const float4*)(src + k), b = *(const float4*)(src + k + 4);
        h[0] = (_Float16)a.x; h[1] = (_Float16)a.y;
        h[2] = (_Float16)a.z; h[3] = (_Float16)a.w;
        h[4] = (_Float16)b.x; h[5] = (_Float16)b.y;
        h[6] = (_Float16)b.z; h[7] = (_Float16)b.w;
      } else {
#pragma unroll
        for (int i = 0; i < 8; ++i) h[i] = (_Float16)0.f;
      }
      *(f16x8*)(dstrow + k) = h;
    }
  }
}

// ---------------------------------------------------------------------------
// Kernel 2: fused convert_x + router + c-columns (unchanged from R5).
// ---------------------------------------------------------------------------
constexpr int RW5 = 16;   // waves per block

__global__ __launch_bounds__(1024) void router_fused5_kernel(
    const float* __restrict__ x, const _Float16* __restrict__ vh,
    const float* __restrict__ router_b, const float* __restrict__ prior,
    const int* __restrict__ active, _Float16* __restrict__ xh) {
  __shared__ float zred[RW5][16][48];   // 48 KB
  const int tid  = threadIdx.x;
  const int lane = tid & 63;
  const int w    = tid >> 6;            // 0..15
  const long t0  = (long)blockIdx.x * 16;
  const int r15  = lane & 15;
  const int kg   = lane >> 4;

  const float*    xp  = x  + (t0 + r15) * H  + w * 256 + kg * 8;
  _Float16*       xhp = xh + (t0 + r15) * KP + w * 256 + kg * 8;
  const _Float16* vp  = vh + (size_t)r15 * H + w * 256 + kg * 8;

  f32x4 acc[3];
  const f32x4 zero = {0.f, 0.f, 0.f, 0.f};
  acc[0] = zero; acc[1] = zero; acc[2] = zero;

#pragma unroll
  for (int c = 0; c < 8; ++c) {
    const int ko = c * 32;
    float4 v0 = *(const float4*)(xp + ko);
    float4 v1 = *(const float4*)(xp + ko + 4);
    f16x8 a;
    a[0] = (_Float16)v0.x; a[1] = (_Float16)v0.y;
    a[2] = (_Float16)v0.z; a[3] = (_Float16)v0.w;
    a[4] = (_Float16)v1.x; a[5] = (_Float16)v1.y;
    a[6] = (_Float16)v1.z; a[7] = (_Float16)v1.w;
    *(f16x8*)(xhp + ko) = a;
#pragma unroll
    for (int nf = 0; nf < 3; ++nf) {
      f16x8 b = *(const f16x8*)(vp + (size_t)nf * 16 * H + ko);
      acc[nf] = __builtin_amdgcn_mfma_f32_16x16x32_f16(a, b, acc[nf], 0, 0, 0);
    }
  }

  // scatter partials: C/D layout col=lane&15 (j), row=(lane>>4)*4+r (token)
#pragma unroll
  for (int nf = 0; nf < 3; ++nf)
#pragma unroll
    for (int r = 0; r < 4; ++r)
      zred[w][kg * 4 + r][nf * 16 + r15] = acc[nf][r];
  __syncthreads();

  // reduce 16 wave-partials: 768 slots, one per thread (tid < 768)
  float s = 0.f;
  int tt = 0, jj = 0;
  if (tid < 16 * 48) {
    tt = tid / 48; jj = tid % 48;
#pragma unroll
    for (int ww = 0; ww < RW5; ++ww) s += zred[ww][tt][jj];
  }
  __syncthreads();
  if (tid < 16 * 48) zred[0][tt][jj] = s;
  __syncthreads();

  // softmax + c-columns + zero pad: thread = (token tt, expert e)
  if (tid < 16 * EA) {
    const int t2 = tid >> 2, e = tid & 3;
    const float* zt = &zred[0][t2][0];
    float le[EA], mx = -1e30f;
#pragma unroll
    for (int e2 = 0; e2 < EA; ++e2) {
      const int ae = active[e2];
      le[e2] = logf(prior[ae] + 1e-12f) + zt[32 + e2] + router_b[ae];
      mx = fmaxf(mx, le[e2]);
    }
    float sum = 0.f;
#pragma unroll
    for (int e2 = 0; e2 < EA; ++e2) sum += expf(le[e2] - mx);
    const float a = expf(le[e] - mx) / sum * SCALING_F;
    f16x8 ch, zz;
#pragma unroll
    for (int r = 0; r < 8; ++r) {
      ch[r] = (_Float16)(a * zt[e * 8 + r]);
      zz[r] = (_Float16)0.f;
    }
    _Float16* xr = xh + (t0 + t2) * KP + H;
    *(f16x8*)(xr + e * 8) = ch;
    *(f16x8*)(xr + 32 + e * 8) = zz;
  }
}

// ---------------------------------------------------------------------------
// Kernel 3: fp16 MFMA GEMM, 256x256 tile, 8-phase-style schedule.
// 512 thr = 8 waves (wr=wave>>2 in 0..1, wc=wave&3 in 0..3); per-wave output
// 128x64 = 8 m-frags x 4 n-frags. LDS: 2 slots x (A 32KB + B 32KB) = 128 KiB.
// Per K-tile t (slot s=t&1): 4 phases q: quadrant (mh=q>>1, nh=q&1):
//   {12 ds_read_b128 (XOR-swizzled, 0-conflict-validated layout);
//    q==0: stage A-halves of tile t+1 -> slot s^1; q==1: stage B-halves;
//    s_barrier; lgkmcnt(0)+sched_barrier; setprio(1); 16 MFMA; setprio(0);
//    q==3: vmcnt(0) (covered by ~3 phases of MFMA); s_barrier}
// Race-freedom: slot s^1 writes issue only after its last readers (tile t-1,
// group t-1 phase 3) passed group t-1's trailing barrier; lands-before-read
// enforced by the end-of-group vmcnt(0).
// ---------------------------------------------------------------------------
constexpr int BM = 256, BN = 256, BK = 64, NT = KP / BK;  // 65 tiles

__global__ __launch_bounds__(512, 2) void gemm_kernel(
    const _Float16* __restrict__ xh, const _Float16* __restrict__ wh,
    const float* __restrict__ b_base, float* __restrict__ out) {
  __shared__ _Float16 As[2][BM * BK];   // 2 x 32 KB
  __shared__ _Float16 Ws[2][BN * BK];   // 2 x 32 KB
  const int tid  = threadIdx.x;
  const int lane = tid & 63;
  const int wave = tid >> 6;            // 0..7
  const int bid  = (int)blockIdx.x;
  const int im = bid >> 4;              // 32 M-tiles
  const int in = bid & 15;              // 16 N-tiles
  const size_t trow0 = (size_t)im * BM;
  const size_t ocol0 = (size_t)in * BN;
  const int wr = wave >> 2;             // 0..1
  const int wc = wave & 3;              // 0..3
  const int r15 = lane & 15;
  const int kg  = lane >> 4;

  f32x4 acc[8][4];
  const f32x4 zero = {0.f, 0.f, 0.f, 0.f};
#pragma unroll
  for (int m = 0; m < 8; ++m)
#pragma unroll
    for (int n = 0; n < 4; ++n) acc[m][n] = zero;

  // stage one 128-row half of A or B into slot s (2 x gload16 / thread).
  // LDS linear dst; source col pre-swizzled so LDS[row][sl] = G[row][sl^(row&7)].
  auto stageA = [&](int s, int t, int h) {
#pragma unroll
    for (int i = 0; i < 2; ++i) {
      const int idx = tid + 512 * i;          // 0..1023
      const int row = idx >> 3;               // 0..127 within half
      const int sg  = (idx & 7) ^ (row & 7);
      gload16(xh + (trow0 + h * 128 + row) * KP + t * 64 + sg * 8,
              &As[s][h * 8192 + idx * 8]);
    }
  };
  auto stageB = [&](int s, int t, int h) {
#pragma unroll
    for (int i = 0; i < 2; ++i) {
      const int idx = tid + 512 * i;
      const int row = idx >> 3;
      const int sg  = (idx & 7) ^ (row & 7);
      gload16(wh + (ocol0 + h * 128 + row) * KP + t * 64 + sg * 8,
              &Ws[s][h * 8192 + idx * 8]);
    }
  };

  // prologue: tile 0 -> slot 0
  stageA(0, 0, 0); stageA(0, 0, 1);
  stageB(0, 0, 0); stageB(0, 0, 1);
  asm volatile("s_waitcnt vmcnt(0)" ::: "memory");
  __builtin_amdgcn_s_barrier();

  for (int t = 0; t < NT; ++t) {
    const int s = t & 1;
    const _Float16* Ab = &As[s][0];
    const _Float16* Bb = &Ws[s][0];
#pragma unroll
    for (int q = 0; q < 4; ++q) {
      const int mh = q >> 1, nh = q & 1;
      // 12 ds_read_b128: quadrant's A frags (4m x 2kk) + B frags (2n x 2kk)
      f16x8 af[4][2], bf[2][2];
#pragma unroll
      for (int m = 0; m < 4; ++m) {
        const int row = wr * 128 + (mh * 4 + m) * 16 + r15;
#pragma unroll
        for (int kk = 0; kk < 2; ++kk) {
          const int slot = (kk * 4 + kg) ^ (row & 7);
          af[m][kk] = *(const f16x8*)(Ab + row * 64 + slot * 8);
        }
      }
#pragma unroll
      for (int n = 0; n < 2; ++n) {
        const int row = wc * 64 + (nh * 2 + n) * 16 + r15;
#pragma unroll
        for (int kk = 0; kk < 2; ++kk) {
          const int slot = (kk * 4 + kg) ^ (row & 7);
          bf[n][kk] = *(const f16x8*)(Bb + row * 64 + slot * 8);
        }
      }
      // front-loaded staging of tile t+1 (phases 0,1) -> max vmcnt cover
      if (t + 1 < NT) {
        if (q == 0)      { stageA(s ^ 1, t + 1, 0); stageA(s ^ 1, t + 1, 1); }
        else if (q == 1) { stageB(s ^ 1, t + 1, 0); stageB(s ^ 1, t + 1, 1); }
      }
      __builtin_amdgcn_s_barrier();
      asm volatile("s_waitcnt lgkmcnt(0)" ::: "memory");
      __builtin_amdgcn_sched_barrier(0);
      __builtin_amdgcn_s_setprio(1);
#pragma unroll
      for (int m = 0; m < 4; ++m)
#pragma unroll
        for (int n = 0; n < 2; ++n)
#pragma unroll
          for (int kk = 0; kk < 2; ++kk)
            acc[mh * 4 + m][nh * 2 + n] = __builtin_amdgcn_mfma_f32_16x16x32_f16(
                af[m][kk], bf[n][kk], acc[mh * 4 + m][nh * 2 + n], 0, 0, 0);
      __builtin_amdgcn_s_setprio(0);
      __builtin_amdgcn_sched_barrier(0);
      if (q == 3)
        asm volatile("s_waitcnt vmcnt(0)" ::: "memory");  // tile t+1 landed
      __builtin_amdgcn_s_barrier();
    }
  }

  // epilogue: C/D layout col=lane&15 (o), row=(lane>>4)*4+j (token)
#pragma unroll
  for (int n = 0; n < 4; ++n) {
    const size_t col = ocol0 + wc * 64 + n * 16 + r15;
    const float bb = b_base[col];
#pragma unroll
    for (int m = 0; m < 8; ++m) {
      const size_t row = trow0 + wr * 128 + m * 16 + kg * 4;
#pragma unroll
      for (int j = 0; j < 4; ++j)
        out[(row + j) * O + col] = acc[m][n][j] + bb;
    }
  }
}

// ---------------------------------------------------------------------------
extern "C" void kernel_launch(void* const* d_in, const int* in_sizes, int n_in,
                              void* d_out, int out_size, void* d_ws, size_t ws_size,
                              hipStream_t stream) {
  const float* x        = (const float*)d_in[0];
  const float* W_base   = (const float*)d_in[1];
  const float* b_base   = (const float*)d_in[2];
  const float* lora_A   = (const float*)d_in[3];
  const float* lora_B   = (const float*)d_in[4];
  const float* router_W = (const float*)d_in[5];
  const float* router_b = (const float*)d_in[6];
  const float* prior    = (const float*)d_in[7];
  const int*   active   = (const int*)d_in[8];
  float* out = (float*)d_out;

  const int M = in_sizes[0] / H;  // 8192 tokens

  char* ws = (char*)d_ws;
  _Float16* xh = (_Float16*)ws;                               // M*KP*2  = 68.2 MB
  _Float16* wh = (_Float16*)(ws + (size_t)M * KP * 2);        // O*KP*2  = 34.1 MB
  _Float16* vh = (_Float16*)(ws + (size_t)M * KP * 2 + (size_t)O * KP * 2);  // 384 KB

  convert_w3_kernel<<<O + 48, 256, 0, stream>>>(W_base, lora_B, lora_A, router_W,
                                                active, wh, vh);
  router_fused5_kernel<<<M / 16, 1024, 0, stream>>>(x, vh, router_b, prior, active, xh);
  gemm_kernel<<<(M / BM) * (O / BN), 512, 0, stream>>>(xh, wh, b_base, out);
}